// Round 4
// baseline (135.972 us; speedup 1.0000x reference)
//
#include <hip/hip_runtime.h>
#include <math.h>

// NCC loss, restructured:
//   sum(cross)  = A - D/225,  A = sum I*J*cnt,  D = sum S_I*S_J
//   sum(I_var)  = B - E/225,  B = sum I*I*cnt,  E = sum S_I^2
//   sum(J_var)  = C - F/225,  C = sum J*J*cnt,  F = sum S_J^2
// where S_X = 15x15 zero-padded box sum of X, cnt(i,j) = ch(i)*cw(j),
// ch(i) = min(i,7)+min(511-i,7)+1.  Only TWO box filters needed.
//
// R4: horizontal-first box filter computed in REGISTERS from aligned float4
// global loads (no raw-pixel LDS staging at all); only (HI,HJ) float2 sums
// go through LDS. Vertical pass = register sliding over 22 conflict-free
// b64 reads. Finalize fused via last-block pattern (memset-initialized
// counter), removing the second kernel dispatch.

#define IMG_H 512
#define IMG_W 512
#define NB    16
#define TW    64            // output cols per block
#define TH    32            // output rows per block
#define SPAN_R 46           // TH + 14 rows of H-sums
#define STR2  65            // float2 per H row (odd -> conflict-free V reads)
#define NTX   8             // 512/64
#define NTY   16            // 512/32
#define NBLK  (NB * NTX * NTY)   // 2048

__device__ __forceinline__ float winw(int i) {
    int a = i < 7 ? i : 7;
    int b = (511 - i) < 7 ? (511 - i) : 7;
    return (float)(a + b + 1);
}

__global__ __launch_bounds__(256) void ncc_main(const float* __restrict__ I,
                                                const float* __restrict__ J,
                                                float* __restrict__ partials,
                                                unsigned* __restrict__ counter,
                                                float* __restrict__ out) {
    __shared__ float2 H[SPAN_R * STR2];   // packed (H_I, H_J)
    __shared__ float redf[4 * 6];
    __shared__ double redd[4 * 6];
    __shared__ int lastflag;

    const int tid = threadIdx.x;
    const int tx = blockIdx.x, ty = blockIdx.y, bz = blockIdx.z;
    const int R0 = ty * TH - 7;          // global row of H tile-row 0
    const int C0 = tx * TW;              // first output col
    const float* Ib = I + (size_t)bz * IMG_H * IMG_W;
    const float* Jb = J + (size_t)bz * IMG_H * IMG_W;

    float a0 = 0.f, a1 = 0.f, a2 = 0.f;

    // ---- H-stage: 46 rows x 4 runs of 16 H-cols; raw span 30 cols loaded
    // as 8 aligned float4 per array; H computed by register sliding sum. ----
    if (tid < SPAN_R * 4) {
        int r = tid >> 2;                // 0..45
        int run = tid & 3;               // 0..3
        int gr = R0 + r;
        int c0 = C0 + run * 16;          // first H col of this run
        int gb = c0 - 8;                 // aligned raw base (c0 % 16 == 0)
        bool rowok = ((unsigned)gr < (unsigned)IMG_H);
        float rI[32], rJ[32];
        #pragma unroll
        for (int q = 0; q < 8; ++q) {
            int gc = gb + q * 4;
            float4 iv = make_float4(0.f, 0.f, 0.f, 0.f);
            float4 jv = make_float4(0.f, 0.f, 0.f, 0.f);
            if (rowok && (unsigned)gc < (unsigned)IMG_W) {
                iv = *reinterpret_cast<const float4*>(Ib + gr * IMG_W + gc);
                jv = *reinterpret_cast<const float4*>(Jb + gr * IMG_W + gc);
            }
            rI[4 * q + 0] = iv.x; rI[4 * q + 1] = iv.y;
            rI[4 * q + 2] = iv.z; rI[4 * q + 3] = iv.w;
            rJ[4 * q + 0] = jv.x; rJ[4 * q + 1] = jv.y;
            rJ[4 * q + 2] = jv.z; rJ[4 * q + 3] = jv.w;
        }
        // A/B/C over this thread's own 16 center cols (rows 7..38 are the
        // tile's 32 output rows; each pixel owned by exactly one thread).
        if (r >= 7 && r < 7 + TH) {
            float wr = winw(gr);
            #pragma unroll
            for (int t = 0; t < 16; ++t) {
                float w = wr * winw(c0 + t);
                float iv = rI[t + 8], jv = rJ[t + 8];
                a0 += iv * jv * w;
                a1 += iv * iv * w;
                a2 += jv * jv * w;
            }
        }
        // H col c0+t needs raw local idx t+1 .. t+15
        float hI = 0.f, hJ = 0.f;
        #pragma unroll
        for (int d = 1; d <= 15; ++d) { hI += rI[d]; hJ += rJ[d]; }
        float2* Hrow = &H[r * STR2 + run * 16];
        Hrow[0] = make_float2(hI, hJ);
        #pragma unroll
        for (int t = 1; t < 16; ++t) {
            hI += rI[t + 15] - rI[t];
            hJ += rJ[t + 15] - rJ[t];
            Hrow[t] = make_float2(hI, hJ);
        }
    }
    __syncthreads();

    // ---- V-stage: thread = (col, 8-row band); register vertical sliding ----
    float a3 = 0.f, a4 = 0.f, a5 = 0.f;
    {
        int c = tid & 63;
        int band = tid >> 6;             // 0..3
        int rb = band * 8;               // output rows rb..rb+7 need H rows rb..rb+21
        float2 win[22];
        #pragma unroll
        for (int i = 0; i < 22; ++i) win[i] = H[(rb + i) * STR2 + c];
        float sI = 0.f, sJ = 0.f;
        #pragma unroll
        for (int i = 0; i < 15; ++i) { sI += win[i].x; sJ += win[i].y; }
        a3 += sI * sJ; a4 += sI * sI; a5 += sJ * sJ;
        #pragma unroll
        for (int i = 1; i < 8; ++i) {
            sI += win[i + 14].x - win[i - 1].x;
            sJ += win[i + 14].y - win[i - 1].y;
            a3 += sI * sJ; a4 += sI * sI; a5 += sJ * sJ;
        }
    }

    // ---- block reduction: wave shuffle then LDS across the 4 waves ----
    float vals[6] = {a0, a1, a2, a3, a4, a5};
    #pragma unroll
    for (int k = 0; k < 6; ++k) {
        float v = vals[k];
        #pragma unroll
        for (int off = 32; off > 0; off >>= 1) v += __shfl_down(v, off, 64);
        vals[k] = v;
    }
    int wave = tid >> 6, lane = tid & 63;
    if (lane == 0) {
        #pragma unroll
        for (int k = 0; k < 6; ++k) redf[wave * 6 + k] = vals[k];
    }
    __syncthreads();
    if (tid == 0) {
        int bidx = (bz * NTY + ty) * NTX + tx;
        #pragma unroll
        for (int k = 0; k < 6; ++k) {
            partials[bidx * 6 + k] = redf[k] + redf[6 + k] + redf[12 + k] + redf[18 + k];
        }
        __threadfence();                         // make partials visible device-wide
        unsigned old = atomicAdd(counter, 1u);   // device-scope
        lastflag = (old == (unsigned)(NBLK - 1)) ? 1 : 0;
    }
    __syncthreads();

    // ---- fused finalize: last block reduces all partials in double ----
    if (lastflag) {
        __threadfence();                 // acquire side
        double acc[6] = {0, 0, 0, 0, 0, 0};
        for (int b = tid; b < NBLK; b += 256) {
            #pragma unroll
            for (int k = 0; k < 6; ++k) acc[k] += (double)partials[b * 6 + k];
        }
        #pragma unroll
        for (int k = 0; k < 6; ++k) {
            double v = acc[k];
            #pragma unroll
            for (int off = 32; off > 0; off >>= 1) v += __shfl_down(v, off, 64);
            acc[k] = v;
        }
        if (lane == 0) {
            #pragma unroll
            for (int k = 0; k < 6; ++k) redd[wave * 6 + k] = acc[k];
        }
        __syncthreads();
        if (tid == 0) {
            double s[6];
            #pragma unroll
            for (int k = 0; k < 6; ++k)
                s[k] = redd[k] + redd[6 + k] + redd[12 + k] + redd[18 + k];
            double A = s[0], Bv = s[1], Cv = s[2], D = s[3], E = s[4], F = s[5];
            double num = A - D / 225.0;
            double varI = Bv - E / 225.0;
            double varJ = Cv - F / 225.0;
            double cc = num / sqrt(varI * varJ);
            out[0] = (float)(-cc);
        }
    }
}

extern "C" void kernel_launch(void* const* d_in, const int* in_sizes, int n_in,
                              void* d_out, int out_size, void* d_ws, size_t ws_size,
                              hipStream_t stream) {
    const float* I = (const float*)d_in[0];
    const float* J = (const float*)d_in[1];
    float* partials = (float*)d_ws;                        // NBLK*6 floats = 48 KB
    unsigned* counter = (unsigned*)((char*)d_ws + NBLK * 6 * sizeof(float));

    hipMemsetAsync(counter, 0, sizeof(unsigned), stream);  // graph-capture-safe
    dim3 grid(NTX, NTY, NB);
    ncc_main<<<grid, 256, 0, stream>>>(I, J, partials, counter, (float*)d_out);
}

// Round 5
// 127.369 us; speedup vs baseline: 1.0675x; 1.0675x over previous
//
#include <hip/hip_runtime.h>
#include <math.h>

// NCC loss, restructured:
//   sum(cross)  = A - D/225,  A = sum I*J*cnt,  D = sum S_I*S_J
//   sum(I_var)  = B - E/225,  B = sum I*I*cnt,  E = sum S_I^2
//   sum(J_var)  = C - F/225,  C = sum J*J*cnt,  F = sum S_J^2
// where S_X = 15x15 zero-padded box sum of X, cnt(i,j) = ch(i)*cw(j),
// ch(i) = min(i,7)+min(511-i,7)+1.  Only TWO box filters needed.
//
// R5 = R3's proven LDS-vectorized 3-stage kernel (90.8 us) + R4's verified
// fused last-block finalize (removes the second dispatch). R4's
// registers-only H-pass is reverted: holding 64 floats/thread spilled to
// scratch (VGPR=48, 80 us, ~0 HBM traffic).

#define IMG_H 512
#define IMG_W 512
#define NB    16
#define TW    64
#define TH    32
#define HALO  7
#define SPAN_R 46           // TH + 14
#define SPAN_C 80           // TW + 16 (aligned halo: C0 = tx*64 - 8)
#define LSTR  80
#define VSTR  82            // odd-granule stride for conflict-free stage-3 b64
#define NTX   8             // 512/64
#define NTY   16            // 512/32
#define NBLK  (NB * NTX * NTY)   // 2048

__device__ __forceinline__ float winw(int i) {
    int a = i < 7 ? i : 7;
    int b = (511 - i) < 7 ? (511 - i) : 7;
    return (float)(a + b + 1);
}

__global__ __launch_bounds__(256) void ncc_main(const float* __restrict__ I,
                                                const float* __restrict__ J,
                                                float* __restrict__ partials,
                                                unsigned* __restrict__ counter,
                                                float* __restrict__ out) {
    __shared__ float lI[SPAN_R * LSTR];
    __shared__ float lJ[SPAN_R * LSTR];
    __shared__ float vI[TH * VSTR];
    __shared__ float vJ[TH * VSTR];
    __shared__ float redf[4 * 6];
    __shared__ double redd[4 * 6];
    __shared__ int lastflag;

    const int tid = threadIdx.x;
    const int tx = blockIdx.x, ty = blockIdx.y, bz = blockIdx.z;
    const int R0 = ty * TH - HALO;
    const int C0 = tx * TW - 8;          // aligned halo start (stored col 0)
    const float* Ib = I + (size_t)bz * IMG_H * IMG_W;
    const float* Jb = J + (size_t)bz * IMG_H * IMG_W;

    float a0 = 0.f, a1 = 0.f, a2 = 0.f;

    // ---- stage 1: 46x80 tile, float4 loads, b128 LDS stores ----
    for (int k = tid; k < SPAN_R * (SPAN_C / 4); k += 256) {
        int r = k / (SPAN_C / 4);
        int q = k - r * (SPAN_C / 4);
        int gr = R0 + r;
        int gc4 = C0 + q * 4;
        float4 iv = make_float4(0.f, 0.f, 0.f, 0.f);
        float4 jv = make_float4(0.f, 0.f, 0.f, 0.f);
        if ((unsigned)gr < (unsigned)IMG_H && (unsigned)gc4 < (unsigned)IMG_W) {
            iv = *reinterpret_cast<const float4*>(Ib + gr * IMG_W + gc4);
            jv = *reinterpret_cast<const float4*>(Jb + gr * IMG_W + gc4);
        }
        reinterpret_cast<float4*>(lI)[r * (LSTR / 4) + q] = iv;
        reinterpret_cast<float4*>(lJ)[r * (LSTR / 4) + q] = jv;
        // interior pixels: stored rows 7..38, stored quads 2..17 (cols 8..71)
        if (r >= HALO && r < HALO + TH && q >= 2 && q < 18) {
            float wr = winw(gr);
            float w0 = wr * winw(gc4 + 0);
            float w1 = wr * winw(gc4 + 1);
            float w2 = wr * winw(gc4 + 2);
            float w3 = wr * winw(gc4 + 3);
            a0 += iv.x * jv.x * w0 + iv.y * jv.y * w1 + iv.z * jv.z * w2 + iv.w * jv.w * w3;
            a1 += iv.x * iv.x * w0 + iv.y * iv.y * w1 + iv.z * iv.z * w2 + iv.w * iv.w * w3;
            a2 += jv.x * jv.x * w0 + jv.y * jv.y * w1 + jv.z * jv.z * w2 + jv.w * jv.w * w3;
        }
    }
    __syncthreads();

    // ---- stage 2: vertical 15-tap sliding sums, column-pair threads, b64 ----
    {
        int p = tid % 40;
        int chunk = tid / 40;
        if (chunk < 6) {
            int r0 = (chunk < 4) ? chunk * 6 : 24 + (chunk - 4) * 4;
            int nr = (chunk < 4) ? 6 : 4;
            const float2* lI2 = reinterpret_cast<const float2*>(lI);
            const float2* lJ2 = reinterpret_cast<const float2*>(lJ);
            float2* vI2 = reinterpret_cast<float2*>(vI);
            float2* vJ2 = reinterpret_cast<float2*>(vJ);
            float2 sI = make_float2(0.f, 0.f), sJ = make_float2(0.f, 0.f);
            #pragma unroll
            for (int dr = 0; dr < 15; ++dr) {
                float2 i2 = lI2[(r0 + dr) * 40 + p];
                float2 j2 = lJ2[(r0 + dr) * 40 + p];
                sI.x += i2.x; sI.y += i2.y;
                sJ.x += j2.x; sJ.y += j2.y;
            }
            vI2[r0 * 41 + p] = sI;
            vJ2[r0 * 41 + p] = sJ;
            for (int r = r0 + 1; r < r0 + nr; ++r) {
                float2 iA = lI2[(r + 14) * 40 + p], iB = lI2[(r - 1) * 40 + p];
                float2 jA = lJ2[(r + 14) * 40 + p], jB = lJ2[(r - 1) * 40 + p];
                sI.x += iA.x - iB.x; sI.y += iA.y - iB.y;
                sJ.x += jA.x - jB.x; sJ.y += jA.y - jB.y;
                vI2[r * 41 + p] = sI;
                vJ2[r * 41 + p] = sJ;
            }
        }
    }
    __syncthreads();

    // ---- stage 3: horizontal sliding over an 8-col run per thread ----
    float a3 = 0.f, a4 = 0.f, a5 = 0.f;
    {
        int r = tid & 31;
        int ch = tid >> 5;
        int c0 = ch * 8;
        int base = r * VSTR + c0;
        const float2* vI2 = reinterpret_cast<const float2*>(vI);
        const float2* vJ2 = reinterpret_cast<const float2*>(vJ);
        float va[22], vb[22];
        va[0] = vI[base + 1];  vb[0] = vJ[base + 1];
        #pragma unroll
        for (int i = 0; i < 10; ++i) {
            float2 x = vI2[(base + 2) / 2 + i];
            float2 y = vJ2[(base + 2) / 2 + i];
            va[1 + 2 * i] = x.x; va[2 + 2 * i] = x.y;
            vb[1 + 2 * i] = y.x; vb[2 + 2 * i] = y.y;
        }
        va[21] = vI[base + 22]; vb[21] = vJ[base + 22];

        float sI = 0.0f, sJ = 0.0f;
        #pragma unroll
        for (int i = 0; i < 15; ++i) { sI += va[i]; sJ += vb[i]; }
        a3 += sI * sJ;
        a4 += sI * sI;
        a5 += sJ * sJ;
        #pragma unroll
        for (int i = 1; i < 8; ++i) {
            sI += va[i + 14] - va[i - 1];
            sJ += vb[i + 14] - vb[i - 1];
            a3 += sI * sJ;
            a4 += sI * sI;
            a5 += sJ * sJ;
        }
    }

    // ---- block reduction: wave shuffle then LDS across the 4 waves ----
    float vals[6] = {a0, a1, a2, a3, a4, a5};
    #pragma unroll
    for (int k = 0; k < 6; ++k) {
        float v = vals[k];
        #pragma unroll
        for (int off = 32; off > 0; off >>= 1) v += __shfl_down(v, off, 64);
        vals[k] = v;
    }
    int wave = tid >> 6, lane = tid & 63;
    if (lane == 0) {
        #pragma unroll
        for (int k = 0; k < 6; ++k) redf[wave * 6 + k] = vals[k];
    }
    __syncthreads();
    if (tid == 0) {
        int bidx = (bz * NTY + ty) * NTX + tx;
        #pragma unroll
        for (int k = 0; k < 6; ++k) {
            partials[bidx * 6 + k] = redf[k] + redf[6 + k] + redf[12 + k] + redf[18 + k];
        }
        __threadfence();                         // release partials device-wide
        unsigned old = atomicAdd(counter, 1u);   // device-scope atomic
        lastflag = (old == (unsigned)(NBLK - 1)) ? 1 : 0;
    }
    __syncthreads();

    // ---- fused finalize: last block reduces all partials in double ----
    if (lastflag) {
        __threadfence();                 // acquire side
        double acc[6] = {0, 0, 0, 0, 0, 0};
        for (int b = tid; b < NBLK; b += 256) {
            #pragma unroll
            for (int k = 0; k < 6; ++k) acc[k] += (double)partials[b * 6 + k];
        }
        #pragma unroll
        for (int k = 0; k < 6; ++k) {
            double v = acc[k];
            #pragma unroll
            for (int off = 32; off > 0; off >>= 1) v += __shfl_down(v, off, 64);
            acc[k] = v;
        }
        if (lane == 0) {
            #pragma unroll
            for (int k = 0; k < 6; ++k) redd[wave * 6 + k] = acc[k];
        }
        __syncthreads();
        if (tid == 0) {
            double s[6];
            #pragma unroll
            for (int k = 0; k < 6; ++k)
                s[k] = redd[k] + redd[6 + k] + redd[12 + k] + redd[18 + k];
            double A = s[0], Bv = s[1], Cv = s[2], D = s[3], E = s[4], F = s[5];
            double num = A - D / 225.0;
            double varI = Bv - E / 225.0;
            double varJ = Cv - F / 225.0;
            double cc = num / sqrt(varI * varJ);
            out[0] = (float)(-cc);
        }
    }
}

extern "C" void kernel_launch(void* const* d_in, const int* in_sizes, int n_in,
                              void* d_out, int out_size, void* d_ws, size_t ws_size,
                              hipStream_t stream) {
    const float* I = (const float*)d_in[0];
    const float* J = (const float*)d_in[1];
    float* partials = (float*)d_ws;                        // NBLK*6 floats = 48 KB
    unsigned* counter = (unsigned*)((char*)d_ws + NBLK * 6 * sizeof(float));

    hipMemsetAsync(counter, 0, sizeof(unsigned), stream);  // graph-capture-safe
    dim3 grid(NTX, NTY, NB);
    ncc_main<<<grid, 256, 0, stream>>>(I, J, partials, counter, (float*)d_out);
}

// Round 6
// 95.705 us; speedup vs baseline: 1.4207x; 1.3309x over previous
//
#include <hip/hip_runtime.h>
#include <math.h>

// NCC loss, restructured:
//   sum(cross)  = A - D/225,  A = sum I*J*cnt,  D = sum S_I*S_J
//   sum(I_var)  = B - E/225,  B = sum I*I*cnt,  E = sum S_I^2
//   sum(J_var)  = C - F/225,  C = sum J*J*cnt,  F = sum S_J^2
// where S_X = 15x15 zero-padded box sum of X, cnt(i,j) = ch(i)*cw(j),
// ch(i) = min(i,7)+min(511-i,7)+1.  Only TWO box filters needed.
//
// R6: R3's proven vectorized 3-stage structure, tile shrunk to 64x16:
// LDS 51->30 KB (3->5 blocks/CU), 2048->4096 blocks (16/CU) to hide the
// per-block serial chain (kernel is latency-bound: all pipes <25%).
// Fused last-block finalize REVERTED: per-block device-scope
// threadfence+atomic cost ~25 us on multi-XCD gfx950 (R5 evidence:
// warm ncc_main 60 us at 176 KB hbm traffic). Two kernels again.

#define IMG_H 512
#define IMG_W 512
#define NB    16
#define TW    64
#define TH    16
#define HALO  7
#define SPAN_R 30           // TH + 14
#define SPAN_C 80           // TW + 16 (aligned halo: C0 = tx*64 - 8)
#define LSTR  80
#define VSTR  82            // odd-granule stride for conflict-free stage-3 b64
#define NTX   8             // 512/64
#define NTY   32            // 512/16
#define NBLK  (NB * NTX * NTY)   // 4096

__device__ __forceinline__ float winw(int i) {
    int a = i < 7 ? i : 7;
    int b = (511 - i) < 7 ? (511 - i) : 7;
    return (float)(a + b + 1);
}

__global__ __launch_bounds__(256) void ncc_main(const float* __restrict__ I,
                                                const float* __restrict__ J,
                                                float* __restrict__ partials) {
    __shared__ float lI[SPAN_R * LSTR];      // 9.4 KB
    __shared__ float lJ[SPAN_R * LSTR];      // 9.4 KB
    __shared__ float vI[TH * VSTR];          // 5.25 KB
    __shared__ float vJ[TH * VSTR];          // 5.25 KB
    __shared__ float redf[4 * 6];

    const int tid = threadIdx.x;
    const int tx = blockIdx.x, ty = blockIdx.y, bz = blockIdx.z;
    const int R0 = ty * TH - HALO;
    const int C0 = tx * TW - 8;          // aligned halo start (stored col 0)
    const float* Ib = I + (size_t)bz * IMG_H * IMG_W;
    const float* Jb = J + (size_t)bz * IMG_H * IMG_W;

    float a0 = 0.f, a1 = 0.f, a2 = 0.f;

    // ---- stage 1: 30x80 tile, float4 loads, b128 LDS stores ----
    // 30 rows x 20 quads = 600 float4 per array.
    for (int k = tid; k < SPAN_R * (SPAN_C / 4); k += 256) {
        int r = k / (SPAN_C / 4);
        int q = k - r * (SPAN_C / 4);
        int gr = R0 + r;
        int gc4 = C0 + q * 4;
        float4 iv = make_float4(0.f, 0.f, 0.f, 0.f);
        float4 jv = make_float4(0.f, 0.f, 0.f, 0.f);
        if ((unsigned)gr < (unsigned)IMG_H && (unsigned)gc4 < (unsigned)IMG_W) {
            iv = *reinterpret_cast<const float4*>(Ib + gr * IMG_W + gc4);
            jv = *reinterpret_cast<const float4*>(Jb + gr * IMG_W + gc4);
        }
        reinterpret_cast<float4*>(lI)[r * (LSTR / 4) + q] = iv;
        reinterpret_cast<float4*>(lJ)[r * (LSTR / 4) + q] = jv;
        // interior pixels: stored rows 7..22, stored quads 2..17 (cols 8..71)
        if (r >= HALO && r < HALO + TH && q >= 2 && q < 18) {
            float wr = winw(gr);
            float w0 = wr * winw(gc4 + 0);
            float w1 = wr * winw(gc4 + 1);
            float w2 = wr * winw(gc4 + 2);
            float w3 = wr * winw(gc4 + 3);
            a0 += iv.x * jv.x * w0 + iv.y * jv.y * w1 + iv.z * jv.z * w2 + iv.w * jv.w * w3;
            a1 += iv.x * iv.x * w0 + iv.y * iv.y * w1 + iv.z * iv.z * w2 + iv.w * iv.w * w3;
            a2 += jv.x * jv.x * w0 + jv.y * jv.y * w1 + jv.z * jv.z * w2 + jv.w * jv.w * w3;
        }
    }
    __syncthreads();

    // ---- stage 2: vertical 15-tap sliding sums, column-pair threads, b64 ----
    // 40 pairs x 6 row-chunks (rows 3,3,3,3,2,2); 240 of 256 threads active.
    {
        int p = tid % 40;
        int chunk = tid / 40;
        if (chunk < 6) {
            int r0 = (chunk < 4) ? chunk * 3 : 12 + (chunk - 4) * 2;
            int nr = (chunk < 4) ? 3 : 2;
            const float2* lI2 = reinterpret_cast<const float2*>(lI);
            const float2* lJ2 = reinterpret_cast<const float2*>(lJ);
            float2* vI2 = reinterpret_cast<float2*>(vI);
            float2* vJ2 = reinterpret_cast<float2*>(vJ);
            float2 sI = make_float2(0.f, 0.f), sJ = make_float2(0.f, 0.f);
            #pragma unroll
            for (int dr = 0; dr < 15; ++dr) {
                float2 i2 = lI2[(r0 + dr) * 40 + p];
                float2 j2 = lJ2[(r0 + dr) * 40 + p];
                sI.x += i2.x; sI.y += i2.y;
                sJ.x += j2.x; sJ.y += j2.y;
            }
            vI2[r0 * 41 + p] = sI;
            vJ2[r0 * 41 + p] = sJ;
            for (int r = r0 + 1; r < r0 + nr; ++r) {
                float2 iA = lI2[(r + 14) * 40 + p], iB = lI2[(r - 1) * 40 + p];
                float2 jA = lJ2[(r + 14) * 40 + p], jB = lJ2[(r - 1) * 40 + p];
                sI.x += iA.x - iB.x; sI.y += iA.y - iB.y;
                sJ.x += jA.x - jB.x; sJ.y += jA.y - jB.y;
                vI2[r * 41 + p] = sI;
                vJ2[r * 41 + p] = sJ;
            }
        }
    }
    __syncthreads();

    // ---- stage 3: horizontal sliding over a 4-col run per thread ----
    // v at stored col s corresponds to "needed" col s-1; output col c uses
    // stored cols c+1..c+15.
    float a3 = 0.f, a4 = 0.f, a5 = 0.f;
    {
        int r = tid & 15;        // output row in tile
        int ch = tid >> 4;       // 0..15 -> 4 output cols each
        int c0 = ch * 4;
        int base = r * VSTR + c0;        // even
        const float2* vI2 = reinterpret_cast<const float2*>(vI);
        const float2* vJ2 = reinterpret_cast<const float2*>(vJ);
        float va[18], vb[18];
        va[0] = vI[base + 1];  vb[0] = vJ[base + 1];
        #pragma unroll
        for (int i = 0; i < 8; ++i) {
            float2 x = vI2[(base + 2) / 2 + i];
            float2 y = vJ2[(base + 2) / 2 + i];
            va[1 + 2 * i] = x.x; va[2 + 2 * i] = x.y;
            vb[1 + 2 * i] = y.x; vb[2 + 2 * i] = y.y;
        }
        va[17] = vI[base + 18]; vb[17] = vJ[base + 18];

        float sI = 0.0f, sJ = 0.0f;
        #pragma unroll
        for (int i = 0; i < 15; ++i) { sI += va[i]; sJ += vb[i]; }
        a3 += sI * sJ;
        a4 += sI * sI;
        a5 += sJ * sJ;
        #pragma unroll
        for (int i = 1; i < 4; ++i) {
            sI += va[i + 14] - va[i - 1];
            sJ += vb[i + 14] - vb[i - 1];
            a3 += sI * sJ;
            a4 += sI * sI;
            a5 += sJ * sJ;
        }
    }

    // ---- block reduction: wave shuffle then LDS across the 4 waves ----
    float vals[6] = {a0, a1, a2, a3, a4, a5};
    #pragma unroll
    for (int k = 0; k < 6; ++k) {
        float v = vals[k];
        #pragma unroll
        for (int off = 32; off > 0; off >>= 1) v += __shfl_down(v, off, 64);
        vals[k] = v;
    }
    int wave = tid >> 6, lane = tid & 63;
    if (lane == 0) {
        #pragma unroll
        for (int k = 0; k < 6; ++k) redf[wave * 6 + k] = vals[k];
    }
    __syncthreads();
    if (tid == 0) {
        int bidx = (bz * NTY + ty) * NTX + tx;
        #pragma unroll
        for (int k = 0; k < 6; ++k) {
            partials[bidx * 6 + k] = redf[k] + redf[6 + k] + redf[12 + k] + redf[18 + k];
        }
    }
}

__global__ __launch_bounds__(256) void ncc_finalize(const float* __restrict__ partials,
                                                    float* __restrict__ out) {
    __shared__ double red[4 * 6];
    int tid = threadIdx.x;
    double acc[6] = {0, 0, 0, 0, 0, 0};
    for (int b = tid; b < NBLK; b += 256) {
        #pragma unroll
        for (int k = 0; k < 6; ++k) acc[k] += (double)partials[b * 6 + k];
    }
    #pragma unroll
    for (int k = 0; k < 6; ++k) {
        double v = acc[k];
        #pragma unroll
        for (int off = 32; off > 0; off >>= 1) v += __shfl_down(v, off, 64);
        acc[k] = v;
    }
    int wave = tid >> 6, lane = tid & 63;
    if (lane == 0) {
        #pragma unroll
        for (int k = 0; k < 6; ++k) red[wave * 6 + k] = acc[k];
    }
    __syncthreads();
    if (tid == 0) {
        double s[6];
        #pragma unroll
        for (int k = 0; k < 6; ++k) s[k] = red[k] + red[6 + k] + red[12 + k] + red[18 + k];
        double A = s[0], Bv = s[1], Cv = s[2], D = s[3], E = s[4], F = s[5];
        double num = A - D / 225.0;
        double varI = Bv - E / 225.0;
        double varJ = Cv - F / 225.0;
        double cc = num / sqrt(varI * varJ);
        out[0] = (float)(-cc);
    }
}

extern "C" void kernel_launch(void* const* d_in, const int* in_sizes, int n_in,
                              void* d_out, int out_size, void* d_ws, size_t ws_size,
                              hipStream_t stream) {
    const float* I = (const float*)d_in[0];
    const float* J = (const float*)d_in[1];
    float* partials = (float*)d_ws;   // NBLK*6 floats = 96 KB

    dim3 grid(NTX, NTY, NB);
    ncc_main<<<grid, 256, 0, stream>>>(I, J, partials);
    ncc_finalize<<<1, 256, 0, stream>>>(partials, (float*)d_out);
}